// Round 11
// baseline (165.995 us; speedup 1.0000x reference)
//
#include <hip/hip_runtime.h>

typedef unsigned int u32;
typedef unsigned short u16;
typedef __attribute__((ext_vector_type(8))) short bf16x8;
typedef __attribute__((ext_vector_type(4))) float f32x4;

constexpr int BATCH = 32;
constexpr int DIM   = 256;
constexpr int NPTS  = 512;
constexpr int NH    = 8;
constexpr int KD    = 16;
constexpr int DHEAD = 64;
constexpr int NH_KD = 128;
constexpr int DH    = 512;

__device__ __forceinline__ float bflo(u32 u){ return __uint_as_float(u << 16); }
__device__ __forceinline__ float bfhi(u32 u){ return __uint_as_float(u & 0xffff0000u); }
__device__ __forceinline__ float bf2f(u16 u){ return __uint_as_float(((u32)u) << 16); }

// HW packed f32->bf16 (RNE).
__device__ __forceinline__ u32 pack2bf(float a, float b){
  u32 r;
  asm("v_cvt_pk_bf16_f32 %0, %1, %2" : "=v"(r) : "v"(a), "v"(b));
  return r;
}
__device__ __forceinline__ u16 f2bf(float f){ return (u16)pack2bf(f, f); }

union B8 { bf16x8 v; uint2 u2[2]; uint4 u4; };

// async global->LDS, 16B per lane. LDS dst wave-uniform; HW writes dst+lane*16.
typedef const __attribute__((address_space(1))) unsigned int gu32_t;
typedef __attribute__((address_space(3))) unsigned int su32_t;
__device__ __forceinline__ void gld16(const u16* src, u16* ldsDst){
  __builtin_amdgcn_global_load_lds((gu32_t*)src, (su32_t*)ldsDst, 16, 0, 0);
}

// 4x4 transpose across a lane quad (bf16-output epilogues only).
__device__ __forceinline__ void quadtr(float v[4], int lq){
  float t[4], y[4];
  #pragma unroll
  for (int r = 0; r < 4; r++) t[r] = __shfl_xor(v[r], 1, 64);
  #pragma unroll
  for (int r = 0; r < 4; r++) y[r] = ((r & 1) == (lq & 1)) ? v[r] : t[r ^ 1];
  #pragma unroll
  for (int r = 0; r < 4; r++) t[r] = __shfl_xor(y[r], 2, 64);
  #pragma unroll
  for (int r = 0; r < 4; r++) v[r] = ((r & 2) == (lq & 2)) ? y[r] : t[r ^ 2];
}

// ---------------------------------------------------------------------------
// K_pre: fused preprocessing (all independent, disjoint outputs):
//   blk [0,640)      : weight scale-fold + bf16 cast
//   blk [640,1664)   : x transpose fp32->bf16 rows
//   blk [1664,2688)  : bias table bf16 S^T C-layout, pre-scaled log2e.
// ---------------------------------------------------------------------------
__global__ __launch_bounds__(256) void k_pre(
    const float* __restrict__ wq, const float* __restrict__ sq,
    const float* __restrict__ wp, const float* __restrict__ sp,
    u32* __restrict__ wqb, u32* __restrict__ pwb,
    const float* __restrict__ x, u16* __restrict__ xbt,
    const float* __restrict__ ab, const int* __restrict__ bidx,
    u32* __restrict__ biasb)
{
  __shared__ u16 T[64*68];
  const int blk = blockIdx.x;
  const int tid = threadIdx.x;

  if (blk < 640){
    int t = blk * 256 + tid;
    if (t < 98304){                      // 768*256/2
      int i = 2*t;
      float s = sq[i >> 8];
      wqb[t] = pack2bf(wq[i]*s, wq[i+1]*s);
    } else {
      int j = t - 98304;                 // 256*512/2
      int i = 2*j;
      float s = sp[i >> 9];
      pwb[j] = pack2bf(wp[i]*s, wp[i+1]*s);
    }
  } else if (blk < 1664){
    const int bk = blk - 640;
    const int b = bk >> 5, ct = (bk >> 3) & 3, nt = bk & 7;
    const int c0 = ct*64, n0 = nt*64;

    const float* xb = x + ((size_t)b*DIM + c0)*NPTS + n0;
    #pragma unroll
    for (int it = 0; it < 4; it++){
      int cc = (tid >> 4) + it*16;
      int nn = (tid & 15) * 4;
      float4 v = *(const float4*)(xb + (size_t)cc*NPTS + nn);
      u32* dst = (u32*)&T[cc*68 + nn];
      dst[0] = pack2bf(v.x, v.y);
      dst[1] = pack2bf(v.z, v.w);
    }
    __syncthreads();
    u16* ob = xbt + ((size_t)b*NPTS + n0)*DIM + c0;
    #pragma unroll
    for (int it = 0; it < 4; it++){
      int nn = (tid >> 4) + it*16;
      int cc = (tid & 15) * 4;
      uint2 w;
      w.x = (u32)T[(cc+0)*68 + nn] | ((u32)T[(cc+1)*68 + nn] << 16);
      w.y = (u32)T[(cc+2)*68 + nn] | ((u32)T[(cc+3)*68 + nn] << 16);
      *(uint2*)(ob + (size_t)nn*DIM + cc) = w;
    }
  } else {
    const float L2E = 1.4426950408889634f;
    const int bk = blk - 1664;
    const int mtg = bk >> 5, ntile = bk & 31;
    const int lane = tid & 63;
    const int h0 = tid >> 6;
    const int qq = lane >> 4;
    const int n = ntile*16 + (lane & 15);
    int idx[4];
    #pragma unroll
    for (int r = 0; r < 4; r++)
      idx[r] = bidx[(size_t)n*NPTS + mtg*16 + qq*4 + r];
    for (int h = h0; h < NH; h += 4){
      float v0 = ab[h*NPTS + idx[0]] * L2E, v1 = ab[h*NPTS + idx[1]] * L2E;
      float v2 = ab[h*NPTS + idx[2]] * L2E, v3 = ab[h*NPTS + idx[3]] * L2E;
      u32* dst = biasb + (((size_t)(h*32 + mtg)*32 + ntile)*64 + lane)*2;
      dst[0] = pack2bf(v0, v1);
      dst[1] = pack2bf(v2, v3);
    }
  }
}

// ---------------------------------------------------------------------------
// K1: qkv MFMA GEMM (R6-proven: register-direct K-loop, XCD-swizzled grid,
// packed bf16 epilogue via quad transpose).
// ---------------------------------------------------------------------------
__global__ __launch_bounds__(256) void k_qkv(
    const u16* __restrict__ xbt, const u16* __restrict__ wqb,
    const float* __restrict__ bias,
    u16* __restrict__ qfb, u16* __restrict__ kb, u16* __restrict__ vb)
{
  const int blk = blockIdx.x;
  const int xcd = blk & 7;
  const int idx = blk >> 3;            // 0..95
  const int pair = xcd*16 + idx/6;     // 0..127 = (b,Nblk)
  const int Mblk = idx % 6;
  const int Nblk = pair & 3;
  const int b    = pair >> 2;

  const int tid = threadIdx.x, wave = tid >> 6, lane = tid & 63;
  const int wm = wave >> 1, wn = wave & 1;
  const int c = lane & 15, q = lane >> 4;
  const int lq = lane & 3;
  const int Mbase = Mblk*128 + wm*64;
  const int Nbase = Nblk*128 + wn*64;

  f32x4 acc[4][4];
  #pragma unroll
  for (int mt = 0; mt < 4; mt++){
    f32x4 bi;
    #pragma unroll
    for (int r = 0; r < 4; r++) bi[r] = bias[Mbase + mt*16 + q*4 + r];
    #pragma unroll
    for (int nt = 0; nt < 4; nt++) acc[mt][nt] = bi;
  }

  const u16* xrow = xbt + (size_t)b*NPTS*DIM;

  for (int kc8 = 0; kc8 < 8; kc8++){
    const int kc = kc8*32;
    bf16x8 aW[4], bX[4];
    #pragma unroll
    for (int mt = 0; mt < 4; mt++)
      aW[mt] = *(const bf16x8*)(wqb + (size_t)(Mbase + mt*16 + c)*DIM + kc + q*8);
    #pragma unroll
    for (int nt = 0; nt < 4; nt++)
      bX[nt] = *(const bf16x8*)(xrow + (size_t)(Nbase + nt*16 + c)*DIM + kc + q*8);
    #pragma unroll
    for (int mt = 0; mt < 4; mt++)
      #pragma unroll
      for (int nt = 0; nt < 4; nt++)
        acc[mt][nt] = __builtin_amdgcn_mfma_f32_16x16x32_bf16(
            aW[mt], bX[nt], acc[mt][nt], 0, 0, 0);
  }

  #pragma unroll
  for (int mt = 0; mt < 4; mt++){
    const int m0 = wm*64 + mt*16 + q*4;          // local m row-group base
    #pragma unroll
    for (int nt = 0; nt < 4; nt++){
      if (Mblk == 1){
        // kb[(bh)*512 + n][16ch]: 4 values are channel-contiguous -> pack.
        const int n = Nbase + nt*16 + c;
        const int hh = wm*4 + mt;
        uint2 w;
        w.x = pack2bf(acc[mt][nt][0], acc[mt][nt][1]);
        w.y = pack2bf(acc[mt][nt][2], acc[mt][nt][3]);
        *(uint2*)(kb + (((size_t)b*NH + hh)*NPTS + n)*16 + q*4) = w;
      } else {
        // transpose to n-contig, then 8B store.
        float v[4];
        #pragma unroll
        for (int r = 0; r < 4; r++) v[r] = acc[mt][nt][r];
        quadtr(v, lq);
        const int nq = Nbase + nt*16 + (c & ~3);  // n quad base (mult of 4)
        uint2 w;
        w.x = pack2bf(v[0], v[1]);
        w.y = pack2bf(v[2], v[3]);
        if (Mblk == 0){
          *(uint2*)(qfb + ((size_t)b*NH_KD + m0 + lq)*NPTS + nq) = w;
        } else {
          const int d = (Mblk - 2)*128 + m0 + lq;
          const int pb = (nq & ~31) | (((nq >> 4) & 1) << 2) | (((nq >> 2) & 3) << 3);
          *(uint2*)(vb + ((size_t)b*DH + d)*NPTS + pb) = w;
        }
      }
    }
  }
}

// ---------------------------------------------------------------------------
// K3: MFMA flash attention + fused depthwise conv. R11: grid (256,8) = 2048
// blocks, ONE ntile per wave (64 pts/block = one z-plane z=tg). Halved
// per-wave register state targets <=64 VGPR so 8 blocks/CU can co-reside
// (double the latency-hiding waves; the R3 version of this experiment lacked
// LDS V dedup and drowned in redundant traffic - that's fixed since R4).
// Window skeleton is the R4/R10-PROVEN one, unchanged: V stage load at
// window top, ds_write at bottom before the single barrier; K+bias bf16
// one-window-ahead register prefetch; exp2; HW cvt_pk.
// Conv: threads <128 compute the block's z-plane (8 outputs each, identical
// static-index tap loop as R10) into QS[64][16].
// ---------------------------------------------------------------------------
__global__ __launch_bounds__(256, 4) void k_attn(
    const u16* __restrict__ qfb, const u16* __restrict__ kb,
    const u16* __restrict__ vb, const u16* __restrict__ biasb,
    const float* __restrict__ dww, const float* __restrict__ dws,
    const float* __restrict__ dwb,
    u16* __restrict__ attnout)
{
  __shared__ u16 VS[2][64][40];          // [buf][d row][32 m + 8 pad]
  __shared__ u16 QS[64][16];             // conv output: [pt_local][head-ch]

  const int hb = blockIdx.x, tg = blockIdx.y;   // tg 0..7 = z-plane
  const int b = hb >> 3, h = hb & 7;
  const int tid = threadIdx.x;
  const int lane = tid & 63, wave = tid >> 6;
  const int c = lane & 15, q = lane >> 4;
  const int bh = b*NH + h;
  const int nt = tg*4 + wave;           // ONE ntile per wave
  const int n0 = nt*16;

  // V staging assignment: 256 threads x 16B covers the 64x32 bf16 tile.
  const int vr = tid >> 2;              // d row 0..63
  const int vc = (tid & 3) * 8;         // m col 0,8,16,24

  const u16* kbh = kb + ((size_t)bh*NPTS)*16;
  const u16* vbh = vb + ((size_t)b*DH + h*DHEAD)*NPTS;
  const u16* bw0 = biasb + (size_t)h*262144 + (size_t)nt*256 + lane*4;

  // ---- prologue part 1: issue window-0 V stage load (latency hides under
  // the conv below).
  bf16x8 sv0 = *(const bf16x8*)(vbh + (size_t)vr*NPTS + vc);

  // ---- fused depthwise conv for this block's z-plane (z = tg):
  // threads <128: thread (y = tid>>4 in 0..7, chl = tid&15) computes the 8
  // x-outputs of row (tg, y). Same static tap loop as R10.
  if (tid < 128){
    const int ry  = (tid >> 4) & 7;
    const int chl = tid & 15;
    const int qch = h*16 + chl;

    float wv[27];
    #pragma unroll
    for (int i = 0; i < 27; i++) wv[i] = dww[qch*27 + i];
    const float sc = dws[qch], bi = dwb[qch];
    const u16* qrow = qfb + ((size_t)b*NH_KD + qch)*NPTS;

    float acc8[8];
    #pragma unroll
    for (int xo = 0; xo < 8; xo++) acc8[xo] = 0.f;

    #pragma unroll
    for (int dz = 0; dz < 3; dz++){
      int zz = tg + dz - 1; if ((unsigned)zz > 7u) continue;
      #pragma unroll
      for (int dy = 0; dy < 3; dy++){
        int yy = ry + dy - 1; if ((unsigned)yy > 7u) continue;
        B8 rvb; rvb.v = *(const bf16x8*)(qrow + zz*64 + yy*8);
        float r[8];
        #pragma unroll
        for (int xo = 0; xo < 8; xo++) r[xo] = bf2f(((const u16*)&rvb)[xo]);
        #pragma unroll
        for (int dx = 0; dx < 3; dx++){
          float w = wv[dz*9 + dy*3 + dx];
          #pragma unroll
          for (int xo = 0; xo < 8; xo++){
            int xx = xo + dx - 1;
            if (xx >= 0 && xx < 8) acc8[xo] += r[xx]*w;
          }
        }
      }
    }
    // fold 1/sqrt(KD)=0.25 and log2(e) (exp -> exp2 below).
    #pragma unroll
    for (int xo = 0; xo < 8; xo++){
      float v = (acc8[xo]*sc + bi) * 0.36067376022224085f;
      QS[ry*8 + xo][chl] = f2bf(v);
    }
  }

  // ---- prologue part 2: V(0) LDS write + window-0 K/bias prefetch.
  *(bf16x8*)&VS[0][vr][vc] = sv0;

  const bf16x8 zfrag = {0,0,0,0,0,0,0,0};
  bf16x8 aK0, aK1;
  uint2 u00, u01;

  auto loadKB = [&](int win, bf16x8& k0, bf16x8& k1, uint2& x00, uint2& x01){
    const int mtg = win*2;
    if (q < 2){
      k0 = *(const bf16x8*)(kbh + (((size_t)(mtg*16 + c)) << 4) + q*8);
      k1 = *(const bf16x8*)(kbh + (((size_t)(mtg*16 + 16 + c)) << 4) + q*8);
    } else { k0 = zfrag; k1 = zfrag; }
    x00 = *(const uint2*)(bw0 + (size_t)mtg*8192);
    x01 = *(const uint2*)(bw0 + (size_t)(mtg+1)*8192);
  };

  loadKB(0, aK0, aK1, u00, u01);
  __syncthreads();

  // ---- Q fragment from the conv LDS tile (one-time, one ntile).
  bf16x8 bQ0 = zfrag;
  if (q < 2)
    bQ0 = *(const bf16x8*)&QS[wave*16 + c][q*8];

  f32x4 O0[4] = {{0,0,0,0},{0,0,0,0},{0,0,0,0},{0,0,0,0}};
  float ls0 = 0.f;

  #pragma unroll 1
  for (int win = 0; win < 16; win++){
    // issue next window's V stage load early (T14: write deferred to bottom)
    const int wnext = (win < 15) ? win + 1 : 15;
    bf16x8 sv = *(const bf16x8*)(vbh + (size_t)vr*NPTS + wnext*32 + vc);

    bf16x8 nK0, nK1;
    uint2 m00, m01;
    if (win < 15)
      loadKB(win+1, nK0, nK1, m00, m01);

    // V fragments from LDS (shared by all waves)
    const int vbuf = win & 1;
    bf16x8 V0 = *(const bf16x8*)&VS[vbuf][ 0 + c][q*8];
    bf16x8 V1 = *(const bf16x8*)&VS[vbuf][16 + c][q*8];
    bf16x8 V2 = *(const bf16x8*)&VS[vbuf][32 + c][q*8];
    bf16x8 V3 = *(const bf16x8*)&VS[vbuf][48 + c][q*8];

    f32x4 c00, c01;
    c00[0]=bflo(u00.x); c00[1]=bfhi(u00.x); c00[2]=bflo(u00.y); c00[3]=bfhi(u00.y);
    c01[0]=bflo(u01.x); c01[1]=bfhi(u01.x); c01[2]=bflo(u01.y); c01[3]=bfhi(u01.y);
    f32x4 S00 = __builtin_amdgcn_mfma_f32_16x16x32_bf16(aK0, bQ0, c00, 0, 0, 0);
    f32x4 S01 = __builtin_amdgcn_mfma_f32_16x16x32_bf16(aK1, bQ0, c01, 0, 0, 0);

    float e0, e1, e2, e3;
    B8 aP0;
    e0 = __builtin_amdgcn_exp2f(S00[0]); e1 = __builtin_amdgcn_exp2f(S00[1]);
    e2 = __builtin_amdgcn_exp2f(S00[2]); e3 = __builtin_amdgcn_exp2f(S00[3]);
    ls0 += (e0 + e1) + (e2 + e3);
    aP0.u4.x = pack2bf(e0, e1); aP0.u4.y = pack2bf(e2, e3);
    e0 = __builtin_amdgcn_exp2f(S01[0]); e1 = __builtin_amdgcn_exp2f(S01[1]);
    e2 = __builtin_amdgcn_exp2f(S01[2]); e3 = __builtin_amdgcn_exp2f(S01[3]);
    ls0 += (e0 + e1) + (e2 + e3);
    aP0.u4.z = pack2bf(e0, e1); aP0.u4.w = pack2bf(e2, e3);

    O0[0] = __builtin_amdgcn_mfma_f32_16x16x32_bf16(aP0.v, V0, O0[0], 0, 0, 0);
    O0[1] = __builtin_amdgcn_mfma_f32_16x16x32_bf16(aP0.v, V1, O0[1], 0, 0, 0);
    O0[2] = __builtin_amdgcn_mfma_f32_16x16x32_bf16(aP0.v, V2, O0[2], 0, 0, 0);
    O0[3] = __builtin_amdgcn_mfma_f32_16x16x32_bf16(aP0.v, V3, O0[3], 0, 0, 0);

    // write next window's V tile to the other buffer, then sync.
    if (win < 15)
      *(bf16x8*)&VS[wnext & 1][vr][vc] = sv;
    __syncthreads();

    aK0 = nK0; aK1 = nK1;
    u00 = m00; u01 = m01;
  }

  ls0 += __shfl_xor(ls0, 16, 64);
  ls0 += __shfl_xor(ls0, 32, 64);
  f32x4 inv0;
  #pragma unroll
  for (int r = 0; r < 4; r++)
    inv0[r] = 1.0f / __shfl(ls0, q*4 + r, 64);

  u16* ao = attnout + ((size_t)(b*NPTS + n0))*DH + h*DHEAD;
  #pragma unroll
  for (int dt = 0; dt < 4; dt++)
    #pragma unroll
    for (int r = 0; r < 4; r++)
      ao[(size_t)(q*4 + r)*DH + dt*16 + c] =
          f2bf(fmaxf(O0[dt][r]*inv0[r], 0.f));
}

// ---------------------------------------------------------------------------
// K4: proj MFMA GEMM (R9-proven): LDS 2-phase pipeline, 128x64 tiles,
// 512 blocks = 2 blocks/CU, XCD swizzle, direct fp32 stores.
// ---------------------------------------------------------------------------
__global__ __launch_bounds__(256) void k_proj(
    const u16* __restrict__ attn, const u16* __restrict__ pwb,
    const float* __restrict__ bias, float* __restrict__ out)
{
  __shared__ u16 As[2][4096];          // 128 rows x 32 cols
  __shared__ u16 Bs[2][2048];          //  64 rows x 32 cols

  const int blk = blockIdx.x;          // 512 blocks, XCD-swizzled
  const int xcd = blk & 7;
  const int idx = blk >> 3;            // 0..63
  const int b    = xcd*4 + (idx >> 4); // 4 b's per XCD
  const int inner = idx & 15;
  const int Nblk = inner >> 1;         // 0..7 (64-wide)
  const int Mblk = inner & 1;          // consecutive pair shares (b,Nblk) B-panel

  const int tid = threadIdx.x, wave = tid >> 6, lane = tid & 63;
  const int wm = wave >> 1, wn = wave & 1;
  const int c = lane & 15, q = lane >> 4;
  const int Mbase = Mblk*128 + wm*64;
  const int Nbase = Nblk*64 + wn*32;

  f32x4 acc[4][2];
  #pragma unroll
  for (int mt = 0; mt < 4; mt++){
    f32x4 bi;
    #pragma unroll
    for (int r = 0; r < 4; r++) bi[r] = bias[Mbase + mt*16 + q*4 + r];
    #pragma unroll
    for (int nt = 0; nt < 2; nt++) acc[mt][nt] = bi;
  }

  const u16* aT = pwb + (size_t)(Mblk*128)*DH;
  const u16* bT = attn + ((size_t)b*NPTS + Nblk*64)*DH;

  const int srow = lane >> 2, scol = (lane & 3)*8;

  auto STAGE = [&](int buf, int kc){
    #pragma unroll
    for (int i = 0; i < 2; i++){
      const int ch = wave*2 + i;       // 8 chunks of 16 rows (A)
      gld16(aT + (size_t)(ch*16 + srow)*DH + kc + scol, &As[buf][ch*512]);
    }
    // B: 4 chunks of 16 rows, one per wave
    gld16(bT + (size_t)(wave*16 + srow)*DH + kc + scol, &Bs[buf][wave*512]);
  };

  STAGE(0, 0);
  __syncthreads();

  int cur = 0;
  #pragma unroll 2
  for (int ks = 0; ks < 16; ks++){
    if (ks < 15) STAGE(cur^1, (ks+1)*32);
    bf16x8 aW[4], bA[2];
    #pragma unroll
    for (int mt = 0; mt < 4; mt++)
      aW[mt] = *(const bf16x8*)&As[cur][(wm*64 + mt*16 + c)*32 + q*8];
    #pragma unroll
    for (int nt = 0; nt < 2; nt++)
      bA[nt] = *(const bf16x8*)&Bs[cur][(wn*32 + nt*16 + c)*32 + q*8];
    #pragma unroll
    for (int mt = 0; mt < 4; mt++)
      #pragma unroll
      for (int nt = 0; nt < 2; nt++)
        acc[mt][nt] = __builtin_amdgcn_mfma_f32_16x16x32_bf16(
            aW[mt], bA[nt], acc[mt][nt], 0, 0, 0);
    __syncthreads();
    cur ^= 1;
  }

  #pragma unroll
  for (int mt = 0; mt < 4; mt++){
    #pragma unroll
    for (int nt = 0; nt < 2; nt++){
      const int n = Nbase + nt*16 + c;
      #pragma unroll
      for (int r = 0; r < 4; r++){
        int o = Mbase + mt*16 + q*4 + r;
        out[((size_t)b*DIM + o)*NPTS + n] = acc[mt][nt][r];
      }
    }
  }
}

// ---------------------------------------------------------------------------
extern "C" void kernel_launch(void* const* d_in, const int* in_sizes, int n_in,
                              void* d_out, int out_size, void* d_ws, size_t ws_size,
                              hipStream_t stream)
{
  const float* x     = (const float*)d_in[0];
  const float* qkv_w = (const float*)d_in[1];
  const float* qkv_s = (const float*)d_in[2];
  const float* qkv_b = (const float*)d_in[3];
  const float* dw_w  = (const float*)d_in[4];
  const float* dw_s  = (const float*)d_in[5];
  const float* dw_b  = (const float*)d_in[6];
  const float* ab    = (const float*)d_in[7];
  const float* pw    = (const float*)d_in[8];
  const float* ps    = (const float*)d_in[9];
  const float* pb    = (const float*)d_in[10];
  const int* bidx    = (const int*)d_in[11];

  char* ws = (char*)d_ws;
  u16*   qfb   = (u16*)  (ws);                  //  4 MB (B,128,512) bf16
  u16*   kb    = (u16*)  (ws + ( 8u << 20));    //  4 MB (B,8,512,16) bf16
  u16*   vb    = (u16*)  (ws + (12u << 20));    // 16 MB (B,512,512) bf16 [b][d][p]
  u16*   attn  = (u16*)  (ws + (28u << 20));    // 16 MB (B,512,512) bf16 rows [n][dh]
  u32*   biasb = (u32*)  (ws + (44u << 20));    //  4 MB (8,32,32,64,4) bf16 S^T layout
  u32*   wqb   = (u32*)  (ws + (48u << 20));    // 384 KB (768,256) bf16
  u32*   pwb   = (u32*)  (ws + (49u << 20));    // 256 KB (256,512) bf16
  u16*   xbt   = (u16*)  (ws + (50u << 20));    //  8 MB (B,512,256) bf16 rows

  k_pre <<<dim3(2688),     256, 0, stream>>>(qkv_w, qkv_s, pw, ps, wqb, pwb,
                                             x, xbt, ab, bidx, biasb);
  k_qkv <<<dim3(768),      256, 0, stream>>>(xbt, (const u16*)wqb, qkv_b, qfb, kb, vb);
  k_attn<<<dim3(256, 8),   256, 0, stream>>>(qfb, kb, vb, (const u16*)biasb,
                                             dw_w, dw_s, dw_b, attn);
  k_proj<<<dim3(512),      256, 0, stream>>>(attn, (const u16*)pwb, pb, (float*)d_out);
}

// Round 12
// 151.317 us; speedup vs baseline: 1.0970x; 1.0970x over previous
//
#include <hip/hip_runtime.h>

typedef unsigned int u32;
typedef unsigned short u16;
typedef __attribute__((ext_vector_type(8))) short bf16x8;
typedef __attribute__((ext_vector_type(4))) float f32x4;

constexpr int BATCH = 32;
constexpr int DIM   = 256;
constexpr int NPTS  = 512;
constexpr int NH    = 8;
constexpr int KD    = 16;
constexpr int DHEAD = 64;
constexpr int NH_KD = 128;
constexpr int DH    = 512;

__device__ __forceinline__ float bflo(u32 u){ return __uint_as_float(u << 16); }
__device__ __forceinline__ float bfhi(u32 u){ return __uint_as_float(u & 0xffff0000u); }
__device__ __forceinline__ float bf2f(u16 u){ return __uint_as_float(((u32)u) << 16); }

// HW packed f32->bf16 (RNE).
__device__ __forceinline__ u32 pack2bf(float a, float b){
  u32 r;
  asm("v_cvt_pk_bf16_f32 %0, %1, %2" : "=v"(r) : "v"(a), "v"(b));
  return r;
}
__device__ __forceinline__ u16 f2bf(float f){ return (u16)pack2bf(f, f); }

union B8 { bf16x8 v; uint2 u2[2]; uint4 u4; };

// async global->LDS, 16B per lane. LDS dst wave-uniform; HW writes dst+lane*16.
typedef const __attribute__((address_space(1))) unsigned int gu32_t;
typedef __attribute__((address_space(3))) unsigned int su32_t;
__device__ __forceinline__ void gld16(const u16* src, u16* ldsDst){
  __builtin_amdgcn_global_load_lds((gu32_t*)src, (su32_t*)ldsDst, 16, 0, 0);
}

// 4x4 transpose across a lane quad (bf16-output epilogues only).
__device__ __forceinline__ void quadtr(float v[4], int lq){
  float t[4], y[4];
  #pragma unroll
  for (int r = 0; r < 4; r++) t[r] = __shfl_xor(v[r], 1, 64);
  #pragma unroll
  for (int r = 0; r < 4; r++) y[r] = ((r & 1) == (lq & 1)) ? v[r] : t[r ^ 1];
  #pragma unroll
  for (int r = 0; r < 4; r++) t[r] = __shfl_xor(y[r], 2, 64);
  #pragma unroll
  for (int r = 0; r < 4; r++) v[r] = ((r & 2) == (lq & 2)) ? y[r] : t[r ^ 2];
}

// ---------------------------------------------------------------------------
// K_pre: fused preprocessing (all independent, disjoint outputs):
//   blk [0,640)      : weight scale-fold + bf16 cast
//   blk [640,1664)   : x transpose fp32->bf16 rows
//   blk [1664,2688)  : bias table bf16 S^T C-layout, pre-scaled log2e.
// ---------------------------------------------------------------------------
__global__ __launch_bounds__(256) void k_pre(
    const float* __restrict__ wq, const float* __restrict__ sq,
    const float* __restrict__ wp, const float* __restrict__ sp,
    u32* __restrict__ wqb, u32* __restrict__ pwb,
    const float* __restrict__ x, u16* __restrict__ xbt,
    const float* __restrict__ ab, const int* __restrict__ bidx,
    u32* __restrict__ biasb)
{
  __shared__ u16 T[64*68];
  const int blk = blockIdx.x;
  const int tid = threadIdx.x;

  if (blk < 640){
    int t = blk * 256 + tid;
    if (t < 98304){                      // 768*256/2
      int i = 2*t;
      float s = sq[i >> 8];
      wqb[t] = pack2bf(wq[i]*s, wq[i+1]*s);
    } else {
      int j = t - 98304;                 // 256*512/2
      int i = 2*j;
      float s = sp[i >> 9];
      pwb[j] = pack2bf(wp[i]*s, wp[i+1]*s);
    }
  } else if (blk < 1664){
    const int bk = blk - 640;
    const int b = bk >> 5, ct = (bk >> 3) & 3, nt = bk & 7;
    const int c0 = ct*64, n0 = nt*64;

    const float* xb = x + ((size_t)b*DIM + c0)*NPTS + n0;
    #pragma unroll
    for (int it = 0; it < 4; it++){
      int cc = (tid >> 4) + it*16;
      int nn = (tid & 15) * 4;
      float4 v = *(const float4*)(xb + (size_t)cc*NPTS + nn);
      u32* dst = (u32*)&T[cc*68 + nn];
      dst[0] = pack2bf(v.x, v.y);
      dst[1] = pack2bf(v.z, v.w);
    }
    __syncthreads();
    u16* ob = xbt + ((size_t)b*NPTS + n0)*DIM + c0;
    #pragma unroll
    for (int it = 0; it < 4; it++){
      int nn = (tid >> 4) + it*16;
      int cc = (tid & 15) * 4;
      uint2 w;
      w.x = (u32)T[(cc+0)*68 + nn] | ((u32)T[(cc+1)*68 + nn] << 16);
      w.y = (u32)T[(cc+2)*68 + nn] | ((u32)T[(cc+3)*68 + nn] << 16);
      *(uint2*)(ob + (size_t)nn*DIM + cc) = w;
    }
  } else {
    const float L2E = 1.4426950408889634f;
    const int bk = blk - 1664;
    const int mtg = bk >> 5, ntile = bk & 31;
    const int lane = tid & 63;
    const int h0 = tid >> 6;
    const int qq = lane >> 4;
    const int n = ntile*16 + (lane & 15);
    int idx[4];
    #pragma unroll
    for (int r = 0; r < 4; r++)
      idx[r] = bidx[(size_t)n*NPTS + mtg*16 + qq*4 + r];
    for (int h = h0; h < NH; h += 4){
      float v0 = ab[h*NPTS + idx[0]] * L2E, v1 = ab[h*NPTS + idx[1]] * L2E;
      float v2 = ab[h*NPTS + idx[2]] * L2E, v3 = ab[h*NPTS + idx[3]] * L2E;
      u32* dst = biasb + (((size_t)(h*32 + mtg)*32 + ntile)*64 + lane)*2;
      dst[0] = pack2bf(v0, v1);
      dst[1] = pack2bf(v2, v3);
    }
  }
}

// ---------------------------------------------------------------------------
// K1: qkv MFMA GEMM, rebuilt on the R9-PROVEN k_proj skeleton: LDS 2-phase
// pipeline (global_load_lds w=16, double-buffered, 1 barrier/step), 128x64
// tiles -> grid 6x8x32 = 1536 blocks = 6 blocks/CU (ample TLP to cover the
// per-step vmcnt drain - fixes R5's low-occupancy failure). B-panel staged
// once per block (register version duplicated it 2x across waves). XCD
// swizzle: all 6 Mblks of a (Nblk,b) panel on one XCD. R6 packed epilogue.
// ---------------------------------------------------------------------------
__global__ __launch_bounds__(256) void k_qkv(
    const u16* __restrict__ xbt, const u16* __restrict__ wqb,
    const float* __restrict__ bias,
    u16* __restrict__ qfb, u16* __restrict__ kb, u16* __restrict__ vb)
{
  __shared__ u16 As[2][4096];          // 128 rows x 32 cols
  __shared__ u16 Bs[2][2048];          //  64 rows x 32 cols

  const int blk = blockIdx.x;          // 1536 blocks, XCD-swizzled
  const int xcd = blk & 7;
  const int idx = blk >> 3;            // 0..191
  const int pair = xcd*32 + idx/6;     // 0..255 = (b,Nblk) panel
  const int Mblk = idx % 6;
  const int Nblk = pair & 7;
  const int b    = pair >> 3;

  const int tid = threadIdx.x, wave = tid >> 6, lane = tid & 63;
  const int wm = wave >> 1, wn = wave & 1;
  const int c = lane & 15, q = lane >> 4;
  const int lq = lane & 3;
  const int Mbase = Mblk*128 + wm*64;
  const int Nbase = Nblk*64 + wn*32;

  f32x4 acc[4][2];
  #pragma unroll
  for (int mt = 0; mt < 4; mt++){
    f32x4 bi;
    #pragma unroll
    for (int r = 0; r < 4; r++) bi[r] = bias[Mbase + mt*16 + q*4 + r];
    #pragma unroll
    for (int nt = 0; nt < 2; nt++) acc[mt][nt] = bi;
  }

  const u16* aT = wqb + (size_t)(Mblk*128)*DIM;
  const u16* bT = xbt + ((size_t)b*NPTS + Nblk*64)*DIM;

  const int srow = lane >> 2, scol = (lane & 3)*8;

  auto STAGE = [&](int buf, int kc){
    #pragma unroll
    for (int i = 0; i < 2; i++){
      const int ch = wave*2 + i;       // A: 8 chunks of 16 rows
      gld16(aT + (size_t)(ch*16 + srow)*DIM + kc + scol, &As[buf][ch*512]);
    }
    // B: 4 chunks of 16 rows, one per wave
    gld16(bT + (size_t)(wave*16 + srow)*DIM + kc + scol, &Bs[buf][wave*512]);
  };

  STAGE(0, 0);
  __syncthreads();

  int cur = 0;
  #pragma unroll 2
  for (int ks = 0; ks < 8; ks++){      // K=256, BK=32
    if (ks < 7) STAGE(cur^1, (ks+1)*32);
    bf16x8 aW[4], bX[2];
    #pragma unroll
    for (int mt = 0; mt < 4; mt++)
      aW[mt] = *(const bf16x8*)&As[cur][(wm*64 + mt*16 + c)*32 + q*8];
    #pragma unroll
    for (int nt = 0; nt < 2; nt++)
      bX[nt] = *(const bf16x8*)&Bs[cur][(wn*32 + nt*16 + c)*32 + q*8];
    #pragma unroll
    for (int mt = 0; mt < 4; mt++)
      #pragma unroll
      for (int nt = 0; nt < 2; nt++)
        acc[mt][nt] = __builtin_amdgcn_mfma_f32_16x16x32_bf16(
            aW[mt], bX[nt], acc[mt][nt], 0, 0, 0);
    __syncthreads();
    cur ^= 1;
  }

  #pragma unroll
  for (int mt = 0; mt < 4; mt++){
    const int m0 = wm*64 + mt*16 + q*4;          // local m row-group base
    #pragma unroll
    for (int nt = 0; nt < 2; nt++){
      if (Mblk == 1){
        // kb[(bh)*512 + n][16ch]: 4 values are channel-contiguous -> pack.
        const int n = Nbase + nt*16 + c;
        const int hh = wm*4 + mt;
        uint2 w;
        w.x = pack2bf(acc[mt][nt][0], acc[mt][nt][1]);
        w.y = pack2bf(acc[mt][nt][2], acc[mt][nt][3]);
        *(uint2*)(kb + (((size_t)b*NH + hh)*NPTS + n)*16 + q*4) = w;
      } else {
        // transpose to n-contig, then 8B store.
        float v[4];
        #pragma unroll
        for (int r = 0; r < 4; r++) v[r] = acc[mt][nt][r];
        quadtr(v, lq);
        const int nq = Nbase + nt*16 + (c & ~3);  // n quad base (mult of 4)
        uint2 w;
        w.x = pack2bf(v[0], v[1]);
        w.y = pack2bf(v[2], v[3]);
        if (Mblk == 0){
          *(uint2*)(qfb + ((size_t)b*NH_KD + m0 + lq)*NPTS + nq) = w;
        } else {
          const int d = (Mblk - 2)*128 + m0 + lq;
          const int pb = (nq & ~31) | (((nq >> 4) & 1) << 2) | (((nq >> 2) & 3) << 3);
          *(uint2*)(vb + ((size_t)b*DH + d)*NPTS + pb) = w;
        }
      }
    }
  }
}

// ---------------------------------------------------------------------------
// K3: MFMA flash attention + fused depthwise conv — exact R10-proven version
// (best measured; R11's 1-ntile/wave TLP experiment regressed and is
// reverted). 2 ntiles/wave, grid (256,4). V double-buffered in LDS, stage
// load at window top, ds_write before the single bottom barrier; K+bias bf16
// one-window-ahead register prefetch; exp2; HW cvt_pk.
// ---------------------------------------------------------------------------
__global__ __launch_bounds__(256, 4) void k_attn(
    const u16* __restrict__ qfb, const u16* __restrict__ kb,
    const u16* __restrict__ vb, const u16* __restrict__ biasb,
    const float* __restrict__ dww, const float* __restrict__ dws,
    const float* __restrict__ dwb,
    u16* __restrict__ attnout)
{
  __shared__ u16 VS[2][64][40];          // [buf][d row][32 m + 8 pad]
  __shared__ u16 QS[128][16];            // conv output: [pt_local][head-ch]

  const int hb = blockIdx.x, tg = blockIdx.y;
  const int b = hb >> 3, h = hb & 7;
  const int tid = threadIdx.x;
  const int lane = tid & 63, wave = tid >> 6;
  const int c = lane & 15, q = lane >> 4;
  const int bh = b*NH + h;
  const int nt0 = tg*8 + wave*2;        // ntiles {nt0, nt0+1}
  const int n0 = nt0*16;

  // V staging assignment: 256 threads x 16B covers the 64x32 bf16 tile.
  const int vr = tid >> 2;              // d row 0..63
  const int vc = (tid & 3) * 8;         // m col 0,8,16,24

  const u16* kbh = kb + ((size_t)bh*NPTS)*16;
  const u16* vbh = vb + ((size_t)b*DH + h*DHEAD)*NPTS;
  const u16* bw0 = biasb + (size_t)h*262144 + (size_t)nt0*256 + lane*4;

  // ---- prologue part 1: issue window-0 V stage load (latency hides under
  // the conv below).
  bf16x8 sv0 = *(const bf16x8*)(vbh + (size_t)vr*NPTS + vc);

  // ---- fused depthwise conv: thread (row = tid>>4, chl = tid&15) computes
  // the 8 x-outputs of spatial row (z0+rz, ry) for head-channel chl.
  {
    const int row = tid >> 4;           // 0..15 = rz*8 + ry
    const int rz  = row >> 3, ry = row & 7;
    const int chl = tid & 15;
    const int qch = h*16 + chl;
    const int z0  = tg*2;

    float wv[27];
    #pragma unroll
    for (int i = 0; i < 27; i++) wv[i] = dww[qch*27 + i];
    const float sc = dws[qch], bi = dwb[qch];
    const u16* qrow = qfb + ((size_t)b*NH_KD + qch)*NPTS;

    float acc8[8];
    #pragma unroll
    for (int xo = 0; xo < 8; xo++) acc8[xo] = 0.f;

    #pragma unroll
    for (int dz = 0; dz < 3; dz++){
      int zz = z0 + rz + dz - 1; if ((unsigned)zz > 7u) continue;
      #pragma unroll
      for (int dy = 0; dy < 3; dy++){
        int yy = ry + dy - 1; if ((unsigned)yy > 7u) continue;
        B8 rvb; rvb.v = *(const bf16x8*)(qrow + zz*64 + yy*8);
        float r[8];
        #pragma unroll
        for (int xo = 0; xo < 8; xo++) r[xo] = bf2f(((const u16*)&rvb)[xo]);
        #pragma unroll
        for (int dx = 0; dx < 3; dx++){
          float w = wv[dz*9 + dy*3 + dx];
          #pragma unroll
          for (int xo = 0; xo < 8; xo++){
            int xx = xo + dx - 1;
            if (xx >= 0 && xx < 8) acc8[xo] += r[xx]*w;
          }
        }
      }
    }
    // fold 1/sqrt(KD)=0.25 and log2(e) (exp -> exp2 below).
    #pragma unroll
    for (int xo = 0; xo < 8; xo++){
      float v = (acc8[xo]*sc + bi) * 0.36067376022224085f;
      QS[row*8 + xo][chl] = f2bf(v);
    }
  }

  // ---- prologue part 2: V(0) LDS write + window-0 K/bias prefetch.
  *(bf16x8*)&VS[0][vr][vc] = sv0;

  const bf16x8 zfrag = {0,0,0,0,0,0,0,0};
  bf16x8 aK0, aK1;
  uint2 u00, u01, u10, u11;

  auto loadKB = [&](int win, bf16x8& k0, bf16x8& k1,
                    uint2& x00, uint2& x01, uint2& x10, uint2& x11){
    const int mtg = win*2;
    if (q < 2){
      k0 = *(const bf16x8*)(kbh + (((size_t)(mtg*16 + c)) << 4) + q*8);
      k1 = *(const bf16x8*)(kbh + (((size_t)(mtg*16 + 16 + c)) << 4) + q*8);
    } else { k0 = zfrag; k1 = zfrag; }
    x00 = *(const uint2*)(bw0 + (size_t)mtg*8192);
    x01 = *(const uint2*)(bw0 + (size_t)(mtg+1)*8192);
    x10 = *(const uint2*)(bw0 + 256 + (size_t)mtg*8192);
    x11 = *(const uint2*)(bw0 + 256 + (size_t)(mtg+1)*8192);
  };

  loadKB(0, aK0, aK1, u00, u01, u10, u11);
  __syncthreads();

  // ---- Q fragments from the conv LDS tile (one-time).
  bf16x8 bQ0 = zfrag, bQ1 = zfrag;
  if (q < 2){
    bQ0 = *(const bf16x8*)&QS[wave*32 + c][q*8];
    bQ1 = *(const bf16x8*)&QS[wave*32 + 16 + c][q*8];
  }

  f32x4 O0[4] = {{0,0,0,0},{0,0,0,0},{0,0,0,0},{0,0,0,0}};
  f32x4 O1[4] = {{0,0,0,0},{0,0,0,0},{0,0,0,0},{0,0,0,0}};
  float ls0 = 0.f, ls1 = 0.f;

  #pragma unroll 1
  for (int win = 0; win < 16; win++){
    // issue next window's V stage load early (T14: write deferred to bottom)
    const int wnext = (win < 15) ? win + 1 : 15;
    bf16x8 sv = *(const bf16x8*)(vbh + (size_t)vr*NPTS + wnext*32 + vc);

    bf16x8 nK0, nK1;
    uint2 m00, m01, m10, m11;
    if (win < 15)
      loadKB(win+1, nK0, nK1, m00, m01, m10, m11);

    // V fragments from LDS (shared by both ntiles, all waves)
    const int vbuf = win & 1;
    bf16x8 V0 = *(const bf16x8*)&VS[vbuf][ 0 + c][q*8];
    bf16x8 V1 = *(const bf16x8*)&VS[vbuf][16 + c][q*8];
    bf16x8 V2 = *(const bf16x8*)&VS[vbuf][32 + c][q*8];
    bf16x8 V3 = *(const bf16x8*)&VS[vbuf][48 + c][q*8];

    f32x4 c00, c01, c10, c11;
    c00[0]=bflo(u00.x); c00[1]=bfhi(u00.x); c00[2]=bflo(u00.y); c00[3]=bfhi(u00.y);
    c01[0]=bflo(u01.x); c01[1]=bfhi(u01.x); c01[2]=bflo(u01.y); c01[3]=bfhi(u01.y);
    c10[0]=bflo(u10.x); c10[1]=bfhi(u10.x); c10[2]=bflo(u10.y); c10[3]=bfhi(u10.y);
    c11[0]=bflo(u11.x); c11[1]=bfhi(u11.x); c11[2]=bflo(u11.y); c11[3]=bfhi(u11.y);
    f32x4 S00 = __builtin_amdgcn_mfma_f32_16x16x32_bf16(aK0, bQ0, c00, 0, 0, 0);
    f32x4 S01 = __builtin_amdgcn_mfma_f32_16x16x32_bf16(aK1, bQ0, c01, 0, 0, 0);
    f32x4 S10 = __builtin_amdgcn_mfma_f32_16x16x32_bf16(aK0, bQ1, c10, 0, 0, 0);
    f32x4 S11 = __builtin_amdgcn_mfma_f32_16x16x32_bf16(aK1, bQ1, c11, 0, 0, 0);

    float e0, e1, e2, e3;
    B8 aP0, aP1;
    e0 = __builtin_amdgcn_exp2f(S00[0]); e1 = __builtin_amdgcn_exp2f(S00[1]);
    e2 = __builtin_amdgcn_exp2f(S00[2]); e3 = __builtin_amdgcn_exp2f(S00[3]);
    ls0 += (e0 + e1) + (e2 + e3);
    aP0.u4.x = pack2bf(e0, e1); aP0.u4.y = pack2bf(e2, e3);
    e0 = __builtin_amdgcn_exp2f(S01[0]); e1 = __builtin_amdgcn_exp2f(S01[1]);
    e2 = __builtin_amdgcn_exp2f(S01[2]); e3 = __builtin_amdgcn_exp2f(S01[3]);
    ls0 += (e0 + e1) + (e2 + e3);
    aP0.u4.z = pack2bf(e0, e1); aP0.u4.w = pack2bf(e2, e3);
    e0 = __builtin_amdgcn_exp2f(S10[0]); e1 = __builtin_amdgcn_exp2f(S10[1]);
    e2 = __builtin_amdgcn_exp2f(S10[2]); e3 = __builtin_amdgcn_exp2f(S10[3]);
    ls1 += (e0 + e1) + (e2 + e3);
    aP1.u4.x = pack2bf(e0, e1); aP1.u4.y = pack2bf(e2, e3);
    e0 = __builtin_amdgcn_exp2f(S11[0]); e1 = __builtin_amdgcn_exp2f(S11[1]);
    e2 = __builtin_amdgcn_exp2f(S11[2]); e3 = __builtin_amdgcn_exp2f(S11[3]);
    ls1 += (e0 + e1) + (e2 + e3);
    aP1.u4.z = pack2bf(e0, e1); aP1.u4.w = pack2bf(e2, e3);

    O0[0] = __builtin_amdgcn_mfma_f32_16x16x32_bf16(aP0.v, V0, O0[0], 0, 0, 0);
    O1[0] = __builtin_amdgcn_mfma_f32_16x16x32_bf16(aP1.v, V0, O1[0], 0, 0, 0);
    O0[1] = __builtin_amdgcn_mfma_f32_16x16x32_bf16(aP0.v, V1, O0[1], 0, 0, 0);
    O1[1] = __builtin_amdgcn_mfma_f32_16x16x32_bf16(aP1.v, V1, O1[1], 0, 0, 0);
    O0[2] = __builtin_amdgcn_mfma_f32_16x16x32_bf16(aP0.v, V2, O0[2], 0, 0, 0);
    O1[2] = __builtin_amdgcn_mfma_f32_16x16x32_bf16(aP1.v, V2, O1[2], 0, 0, 0);
    O0[3] = __builtin_amdgcn_mfma_f32_16x16x32_bf16(aP0.v, V3, O0[3], 0, 0, 0);
    O1[3] = __builtin_amdgcn_mfma_f32_16x16x32_bf16(aP1.v, V3, O1[3], 0, 0, 0);

    // write next window's V tile to the other buffer, then sync.
    if (win < 15)
      *(bf16x8*)&VS[wnext & 1][vr][vc] = sv;
    __syncthreads();

    aK0 = nK0; aK1 = nK1;
    u00 = m00; u01 = m01; u10 = m10; u11 = m11;
  }

  ls0 += __shfl_xor(ls0, 16, 64);
  ls0 += __shfl_xor(ls0, 32, 64);
  ls1 += __shfl_xor(ls1, 16, 64);
  ls1 += __shfl_xor(ls1, 32, 64);
  f32x4 inv0, inv1;
  #pragma unroll
  for (int r = 0; r < 4; r++){
    inv0[r] = 1.0f / __shfl(ls0, q*4 + r, 64);
    inv1[r] = 1.0f / __shfl(ls1, q*4 + r, 64);
  }

  u16* ao = attnout + ((size_t)(b*NPTS + n0))*DH + h*DHEAD;
  #pragma unroll
  for (int dt = 0; dt < 4; dt++)
    #pragma unroll
    for (int r = 0; r < 4; r++){
      ao[(size_t)(q*4 + r)*DH + dt*16 + c] =
          f2bf(fmaxf(O0[dt][r]*inv0[r], 0.f));
      ao[(size_t)(16 + q*4 + r)*DH + dt*16 + c] =
          f2bf(fmaxf(O1[dt][r]*inv1[r], 0.f));
    }
}

// ---------------------------------------------------------------------------
// K4: proj MFMA GEMM (R9-proven): LDS 2-phase pipeline, 128x64 tiles,
// 512 blocks = 2 blocks/CU, XCD swizzle, direct fp32 stores.
// ---------------------------------------------------------------------------
__global__ __launch_bounds__(256) void k_proj(
    const u16* __restrict__ attn, const u16* __restrict__ pwb,
    const float* __restrict__ bias, float* __restrict__ out)
{
  __shared__ u16 As[2][4096];          // 128 rows x 32 cols
  __shared__ u16 Bs[2][2048];          //  64 rows x 32 cols

  const int blk = blockIdx.x;          // 512 blocks, XCD-swizzled
  const int xcd = blk & 7;
  const int idx = blk >> 3;            // 0..63
  const int b    = xcd*4 + (idx >> 4); // 4 b's per XCD
  const int inner = idx & 15;
  const int Nblk = inner >> 1;         // 0..7 (64-wide)
  const int Mblk = inner & 1;          // consecutive pair shares (b,Nblk) B-panel

  const int tid = threadIdx.x, wave = tid >> 6, lane = tid & 63;
  const int wm = wave >> 1, wn = wave & 1;
  const int c = lane & 15, q = lane >> 4;
  const int Mbase = Mblk*128 + wm*64;
  const int Nbase = Nblk*64 + wn*32;

  f32x4 acc[4][2];
  #pragma unroll
  for (int mt = 0; mt < 4; mt++){
    f32x4 bi;
    #pragma unroll
    for (int r = 0; r < 4; r++) bi[r] = bias[Mbase + mt*16 + q*4 + r];
    #pragma unroll
    for (int nt = 0; nt < 2; nt++) acc[mt][nt] = bi;
  }

  const u16* aT = pwb + (size_t)(Mblk*128)*DH;
  const u16* bT = attn + ((size_t)b*NPTS + Nblk*64)*DH;

  const int srow = lane >> 2, scol = (lane & 3)*8;

  auto STAGE = [&](int buf, int kc){
    #pragma unroll
    for (int i = 0; i < 2; i++){
      const int ch = wave*2 + i;       // 8 chunks of 16 rows (A)
      gld16(aT + (size_t)(ch*16 + srow)*DH + kc + scol, &As[buf][ch*512]);
    }
    // B: 4 chunks of 16 rows, one per wave
    gld16(bT + (size_t)(wave*16 + srow)*DH + kc + scol, &Bs[buf][wave*512]);
  };

  STAGE(0, 0);
  __syncthreads();

  int cur = 0;
  #pragma unroll 2
  for (int ks = 0; ks < 16; ks++){
    if (ks < 15) STAGE(cur^1, (ks+1)*32);
    bf16x8 aW[4], bA[2];
    #pragma unroll
    for (int mt = 0; mt < 4; mt++)
      aW[mt] = *(const bf16x8*)&As[cur][(wm*64 + mt*16 + c)*32 + q*8];
    #pragma unroll
    for (int nt = 0; nt < 2; nt++)
      bA[nt] = *(const bf16x8*)&Bs[cur][(wn*32 + nt*16 + c)*32 + q*8];
    #pragma unroll
    for (int mt = 0; mt < 4; mt++)
      #pragma unroll
      for (int nt = 0; nt < 2; nt++)
        acc[mt][nt] = __builtin_amdgcn_mfma_f32_16x16x32_bf16(
            aW[mt], bA[nt], acc[mt][nt], 0, 0, 0);
    __syncthreads();
    cur ^= 1;
  }

  #pragma unroll
  for (int mt = 0; mt < 4; mt++){
    #pragma unroll
    for (int nt = 0; nt < 2; nt++){
      const int n = Nbase + nt*16 + c;
      #pragma unroll
      for (int r = 0; r < 4; r++){
        int o = Mbase + mt*16 + q*4 + r;
        out[((size_t)b*DIM + o)*NPTS + n] = acc[mt][nt][r];
      }
    }
  }
}

// ---------------------------------------------------------------------------
extern "C" void kernel_launch(void* const* d_in, const int* in_sizes, int n_in,
                              void* d_out, int out_size, void* d_ws, size_t ws_size,
                              hipStream_t stream)
{
  const float* x     = (const float*)d_in[0];
  const float* qkv_w = (const float*)d_in[1];
  const float* qkv_s = (const float*)d_in[2];
  const float* qkv_b = (const float*)d_in[3];
  const float* dw_w  = (const float*)d_in[4];
  const float* dw_s  = (const float*)d_in[5];
  const float* dw_b  = (const float*)d_in[6];
  const float* ab    = (const float*)d_in[7];
  const float* pw    = (const float*)d_in[8];
  const float* ps    = (const float*)d_in[9];
  const float* pb    = (const float*)d_in[10];
  const int* bidx    = (const int*)d_in[11];

  char* ws = (char*)d_ws;
  u16*   qfb   = (u16*)  (ws);                  //  4 MB (B,128,512) bf16
  u16*   kb    = (u16*)  (ws + ( 8u << 20));    //  4 MB (B,8,512,16) bf16
  u16*   vb    = (u16*)  (ws + (12u << 20));    // 16 MB (B,512,512) bf16 [b][d][p]
  u16*   attn  = (u16*)  (ws + (28u << 20));    // 16 MB (B,512,512) bf16 rows [n][dh]
  u32*   biasb = (u32*)  (ws + (44u << 20));    //  4 MB (8,32,32,64,4) bf16 S^T layout
  u32*   wqb   = (u32*)  (ws + (48u << 20));    // 384 KB (768,256) bf16
  u32*   pwb   = (u32*)  (ws + (49u << 20));    // 256 KB (256,512) bf16
  u16*   xbt   = (u16*)  (ws + (50u << 20));    //  8 MB (B,512,256) bf16 rows

  k_pre <<<dim3(2688),     256, 0, stream>>>(qkv_w, qkv_s, pw, ps, wqb, pwb,
                                             x, xbt, ab, bidx, biasb);
  k_qkv <<<dim3(1536),     256, 0, stream>>>(xbt, (const u16*)wqb, qkv_b, qfb, kb, vb);
  k_attn<<<dim3(256, 4),   256, 0, stream>>>(qfb, kb, vb, (const u16*)biasb,
                                             dw_w, dw_s, dw_b, attn);
  k_proj<<<dim3(512),      256, 0, stream>>>(attn, (const u16*)pwb, pb, (float*)d_out);
}

// Round 13
// 150.075 us; speedup vs baseline: 1.1061x; 1.0083x over previous
//
#include <hip/hip_runtime.h>

typedef unsigned int u32;
typedef unsigned short u16;
typedef __attribute__((ext_vector_type(8))) short bf16x8;
typedef __attribute__((ext_vector_type(4))) float f32x4;

constexpr int BATCH = 32;
constexpr int DIM   = 256;
constexpr int NPTS  = 512;
constexpr int NH    = 8;
constexpr int KD    = 16;
constexpr int DHEAD = 64;
constexpr int NH_KD = 128;
constexpr int DH    = 512;

__device__ __forceinline__ float bflo(u32 u){ return __uint_as_float(u << 16); }
__device__ __forceinline__ float bfhi(u32 u){ return __uint_as_float(u & 0xffff0000u); }
__device__ __forceinline__ float bf2f(u16 u){ return __uint_as_float(((u32)u) << 16); }

// HW packed f32->bf16 (RNE).
__device__ __forceinline__ u32 pack2bf(float a, float b){
  u32 r;
  asm("v_cvt_pk_bf16_f32 %0, %1, %2" : "=v"(r) : "v"(a), "v"(b));
  return r;
}
__device__ __forceinline__ u16 f2bf(float f){ return (u16)pack2bf(f, f); }

union B8 { bf16x8 v; uint2 u2[2]; uint4 u4; };

// async global->LDS, 16B per lane. LDS dst wave-uniform; HW writes dst+lane*16.
typedef const __attribute__((address_space(1))) unsigned int gu32_t;
typedef __attribute__((address_space(3))) unsigned int su32_t;
__device__ __forceinline__ void gld16(const u16* src, u16* ldsDst){
  __builtin_amdgcn_global_load_lds((gu32_t*)src, (su32_t*)ldsDst, 16, 0, 0);
}

// 4x4 transpose across a lane quad (bf16-output epilogues only).
__device__ __forceinline__ void quadtr(float v[4], int lq){
  float t[4], y[4];
  #pragma unroll
  for (int r = 0; r < 4; r++) t[r] = __shfl_xor(v[r], 1, 64);
  #pragma unroll
  for (int r = 0; r < 4; r++) y[r] = ((r & 1) == (lq & 1)) ? v[r] : t[r ^ 1];
  #pragma unroll
  for (int r = 0; r < 4; r++) t[r] = __shfl_xor(y[r], 2, 64);
  #pragma unroll
  for (int r = 0; r < 4; r++) v[r] = ((r & 2) == (lq & 2)) ? y[r] : t[r ^ 2];
}

// ---------------------------------------------------------------------------
// K_pre: fused preprocessing (all independent, disjoint outputs):
//   blk [0,640)      : weight scale-fold + bf16 cast
//   blk [640,1664)   : x transpose fp32->bf16 rows
//   blk [1664,2688)  : bias table bf16 S^T C-layout, pre-scaled log2e.
// ---------------------------------------------------------------------------
__global__ __launch_bounds__(256) void k_pre(
    const float* __restrict__ wq, const float* __restrict__ sq,
    const float* __restrict__ wp, const float* __restrict__ sp,
    u32* __restrict__ wqb, u32* __restrict__ pwb,
    const float* __restrict__ x, u16* __restrict__ xbt,
    const float* __restrict__ ab, const int* __restrict__ bidx,
    u32* __restrict__ biasb)
{
  __shared__ u16 T[64*68];
  const int blk = blockIdx.x;
  const int tid = threadIdx.x;

  if (blk < 640){
    int t = blk * 256 + tid;
    if (t < 98304){                      // 768*256/2
      int i = 2*t;
      float s = sq[i >> 8];
      wqb[t] = pack2bf(wq[i]*s, wq[i+1]*s);
    } else {
      int j = t - 98304;                 // 256*512/2
      int i = 2*j;
      float s = sp[i >> 9];
      pwb[j] = pack2bf(wp[i]*s, wp[i+1]*s);
    }
  } else if (blk < 1664){
    const int bk = blk - 640;
    const int b = bk >> 5, ct = (bk >> 3) & 3, nt = bk & 7;
    const int c0 = ct*64, n0 = nt*64;

    const float* xb = x + ((size_t)b*DIM + c0)*NPTS + n0;
    #pragma unroll
    for (int it = 0; it < 4; it++){
      int cc = (tid >> 4) + it*16;
      int nn = (tid & 15) * 4;
      float4 v = *(const float4*)(xb + (size_t)cc*NPTS + nn);
      u32* dst = (u32*)&T[cc*68 + nn];
      dst[0] = pack2bf(v.x, v.y);
      dst[1] = pack2bf(v.z, v.w);
    }
    __syncthreads();
    u16* ob = xbt + ((size_t)b*NPTS + n0)*DIM + c0;
    #pragma unroll
    for (int it = 0; it < 4; it++){
      int nn = (tid >> 4) + it*16;
      int cc = (tid & 15) * 4;
      uint2 w;
      w.x = (u32)T[(cc+0)*68 + nn] | ((u32)T[(cc+1)*68 + nn] << 16);
      w.y = (u32)T[(cc+2)*68 + nn] | ((u32)T[(cc+3)*68 + nn] << 16);
      *(uint2*)(ob + (size_t)nn*DIM + cc) = w;
    }
  } else {
    const float L2E = 1.4426950408889634f;
    const int bk = blk - 1664;
    const int mtg = bk >> 5, ntile = bk & 31;
    const int lane = tid & 63;
    const int h0 = tid >> 6;
    const int qq = lane >> 4;
    const int n = ntile*16 + (lane & 15);
    int idx[4];
    #pragma unroll
    for (int r = 0; r < 4; r++)
      idx[r] = bidx[(size_t)n*NPTS + mtg*16 + qq*4 + r];
    for (int h = h0; h < NH; h += 4){
      float v0 = ab[h*NPTS + idx[0]] * L2E, v1 = ab[h*NPTS + idx[1]] * L2E;
      float v2 = ab[h*NPTS + idx[2]] * L2E, v3 = ab[h*NPTS + idx[3]] * L2E;
      u32* dst = biasb + (((size_t)(h*32 + mtg)*32 + ntile)*64 + lane)*2;
      dst[0] = pack2bf(v0, v1);
      dst[1] = pack2bf(v2, v3);
    }
  }
}

// ---------------------------------------------------------------------------
// K1: qkv MFMA GEMM (R12-proven): LDS 2-phase pipeline, 128x64 tiles,
// 1536 blocks = 6 blocks/CU, XCD swizzle, packed bf16 epilogue.
// ---------------------------------------------------------------------------
__global__ __launch_bounds__(256) void k_qkv(
    const u16* __restrict__ xbt, const u16* __restrict__ wqb,
    const float* __restrict__ bias,
    u16* __restrict__ qfb, u16* __restrict__ kb, u16* __restrict__ vb)
{
  __shared__ u16 As[2][4096];          // 128 rows x 32 cols
  __shared__ u16 Bs[2][2048];          //  64 rows x 32 cols

  const int blk = blockIdx.x;          // 1536 blocks, XCD-swizzled
  const int xcd = blk & 7;
  const int idx = blk >> 3;            // 0..191
  const int pair = xcd*32 + idx/6;     // 0..255 = (b,Nblk) panel
  const int Mblk = idx % 6;
  const int Nblk = pair & 7;
  const int b    = pair >> 3;

  const int tid = threadIdx.x, wave = tid >> 6, lane = tid & 63;
  const int wm = wave >> 1, wn = wave & 1;
  const int c = lane & 15, q = lane >> 4;
  const int lq = lane & 3;
  const int Mbase = Mblk*128 + wm*64;
  const int Nbase = Nblk*64 + wn*32;

  f32x4 acc[4][2];
  #pragma unroll
  for (int mt = 0; mt < 4; mt++){
    f32x4 bi;
    #pragma unroll
    for (int r = 0; r < 4; r++) bi[r] = bias[Mbase + mt*16 + q*4 + r];
    #pragma unroll
    for (int nt = 0; nt < 2; nt++) acc[mt][nt] = bi;
  }

  const u16* aT = wqb + (size_t)(Mblk*128)*DIM;
  const u16* bT = xbt + ((size_t)b*NPTS + Nblk*64)*DIM;

  const int srow = lane >> 2, scol = (lane & 3)*8;

  auto STAGE = [&](int buf, int kc){
    #pragma unroll
    for (int i = 0; i < 2; i++){
      const int ch = wave*2 + i;       // A: 8 chunks of 16 rows
      gld16(aT + (size_t)(ch*16 + srow)*DIM + kc + scol, &As[buf][ch*512]);
    }
    // B: 4 chunks of 16 rows, one per wave
    gld16(bT + (size_t)(wave*16 + srow)*DIM + kc + scol, &Bs[buf][wave*512]);
  };

  STAGE(0, 0);
  __syncthreads();

  int cur = 0;
  #pragma unroll 2
  for (int ks = 0; ks < 8; ks++){      // K=256, BK=32
    if (ks < 7) STAGE(cur^1, (ks+1)*32);
    bf16x8 aW[4], bX[2];
    #pragma unroll
    for (int mt = 0; mt < 4; mt++)
      aW[mt] = *(const bf16x8*)&As[cur][(wm*64 + mt*16 + c)*32 + q*8];
    #pragma unroll
    for (int nt = 0; nt < 2; nt++)
      bX[nt] = *(const bf16x8*)&Bs[cur][(wn*32 + nt*16 + c)*32 + q*8];
    #pragma unroll
    for (int mt = 0; mt < 4; mt++)
      #pragma unroll
      for (int nt = 0; nt < 2; nt++)
        acc[mt][nt] = __builtin_amdgcn_mfma_f32_16x16x32_bf16(
            aW[mt], bX[nt], acc[mt][nt], 0, 0, 0);
    __syncthreads();
    cur ^= 1;
  }

  #pragma unroll
  for (int mt = 0; mt < 4; mt++){
    const int m0 = wm*64 + mt*16 + q*4;          // local m row-group base
    #pragma unroll
    for (int nt = 0; nt < 2; nt++){
      if (Mblk == 1){
        // kb[(bh)*512 + n][16ch]: 4 values are channel-contiguous -> pack.
        const int n = Nbase + nt*16 + c;
        const int hh = wm*4 + mt;
        uint2 w;
        w.x = pack2bf(acc[mt][nt][0], acc[mt][nt][1]);
        w.y = pack2bf(acc[mt][nt][2], acc[mt][nt][3]);
        *(uint2*)(kb + (((size_t)b*NH + hh)*NPTS + n)*16 + q*4) = w;
      } else {
        // transpose to n-contig, then 8B store.
        float v[4];
        #pragma unroll
        for (int r = 0; r < 4; r++) v[r] = acc[mt][nt][r];
        quadtr(v, lq);
        const int nq = Nbase + nt*16 + (c & ~3);  // n quad base (mult of 4)
        uint2 w;
        w.x = pack2bf(v[0], v[1]);
        w.y = pack2bf(v[2], v[3]);
        if (Mblk == 0){
          *(uint2*)(qfb + ((size_t)b*NH_KD + m0 + lq)*NPTS + nq) = w;
        } else {
          const int d = (Mblk - 2)*128 + m0 + lq;
          const int pb = (nq & ~31) | (((nq >> 4) & 1) << 2) | (((nq >> 2) & 3) << 3);
          *(uint2*)(vb + ((size_t)b*DH + d)*NPTS + pb) = w;
        }
      }
    }
  }
}

// ---------------------------------------------------------------------------
// K3: MFMA flash attention + fused depthwise conv (R10/R12-proven skeleton).
// This round: ISOLATED T5 s_setprio around the two MFMA clusters — blocks on
// a CU are not barrier-synced with each other, so a wave entering its MFMA
// phase gets scheduler preference over other blocks' load-issue phases.
// Everything else unchanged.
// ---------------------------------------------------------------------------
__global__ __launch_bounds__(256, 4) void k_attn(
    const u16* __restrict__ qfb, const u16* __restrict__ kb,
    const u16* __restrict__ vb, const u16* __restrict__ biasb,
    const float* __restrict__ dww, const float* __restrict__ dws,
    const float* __restrict__ dwb,
    u16* __restrict__ attnout)
{
  __shared__ u16 VS[2][64][40];          // [buf][d row][32 m + 8 pad]
  __shared__ u16 QS[128][16];            // conv output: [pt_local][head-ch]

  const int hb = blockIdx.x, tg = blockIdx.y;
  const int b = hb >> 3, h = hb & 7;
  const int tid = threadIdx.x;
  const int lane = tid & 63, wave = tid >> 6;
  const int c = lane & 15, q = lane >> 4;
  const int bh = b*NH + h;
  const int nt0 = tg*8 + wave*2;        // ntiles {nt0, nt0+1}
  const int n0 = nt0*16;

  // V staging assignment: 256 threads x 16B covers the 64x32 bf16 tile.
  const int vr = tid >> 2;              // d row 0..63
  const int vc = (tid & 3) * 8;         // m col 0,8,16,24

  const u16* kbh = kb + ((size_t)bh*NPTS)*16;
  const u16* vbh = vb + ((size_t)b*DH + h*DHEAD)*NPTS;
  const u16* bw0 = biasb + (size_t)h*262144 + (size_t)nt0*256 + lane*4;

  // ---- prologue part 1: issue window-0 V stage load (latency hides under
  // the conv below).
  bf16x8 sv0 = *(const bf16x8*)(vbh + (size_t)vr*NPTS + vc);

  // ---- fused depthwise conv: thread (row = tid>>4, chl = tid&15) computes
  // the 8 x-outputs of spatial row (z0+rz, ry) for head-channel chl.
  {
    const int row = tid >> 4;           // 0..15 = rz*8 + ry
    const int rz  = row >> 3, ry = row & 7;
    const int chl = tid & 15;
    const int qch = h*16 + chl;
    const int z0  = tg*2;

    float wv[27];
    #pragma unroll
    for (int i = 0; i < 27; i++) wv[i] = dww[qch*27 + i];
    const float sc = dws[qch], bi = dwb[qch];
    const u16* qrow = qfb + ((size_t)b*NH_KD + qch)*NPTS;

    float acc8[8];
    #pragma unroll
    for (int xo = 0; xo < 8; xo++) acc8[xo] = 0.f;

    #pragma unroll
    for (int dz = 0; dz < 3; dz++){
      int zz = z0 + rz + dz - 1; if ((unsigned)zz > 7u) continue;
      #pragma unroll
      for (int dy = 0; dy < 3; dy++){
        int yy = ry + dy - 1; if ((unsigned)yy > 7u) continue;
        B8 rvb; rvb.v = *(const bf16x8*)(qrow + zz*64 + yy*8);
        float r[8];
        #pragma unroll
        for (int xo = 0; xo < 8; xo++) r[xo] = bf2f(((const u16*)&rvb)[xo]);
        #pragma unroll
        for (int dx = 0; dx < 3; dx++){
          float w = wv[dz*9 + dy*3 + dx];
          #pragma unroll
          for (int xo = 0; xo < 8; xo++){
            int xx = xo + dx - 1;
            if (xx >= 0 && xx < 8) acc8[xo] += r[xx]*w;
          }
        }
      }
    }
    // fold 1/sqrt(KD)=0.25 and log2(e) (exp -> exp2 below).
    #pragma unroll
    for (int xo = 0; xo < 8; xo++){
      float v = (acc8[xo]*sc + bi) * 0.36067376022224085f;
      QS[row*8 + xo][chl] = f2bf(v);
    }
  }

  // ---- prologue part 2: V(0) LDS write + window-0 K/bias prefetch.
  *(bf16x8*)&VS[0][vr][vc] = sv0;

  const bf16x8 zfrag = {0,0,0,0,0,0,0,0};
  bf16x8 aK0, aK1;
  uint2 u00, u01, u10, u11;

  auto loadKB = [&](int win, bf16x8& k0, bf16x8& k1,
                    uint2& x00, uint2& x01, uint2& x10, uint2& x11){
    const int mtg = win*2;
    if (q < 2){
      k0 = *(const bf16x8*)(kbh + (((size_t)(mtg*16 + c)) << 4) + q*8);
      k1 = *(const bf16x8*)(kbh + (((size_t)(mtg*16 + 16 + c)) << 4) + q*8);
    } else { k0 = zfrag; k1 = zfrag; }
    x00 = *(const uint2*)(bw0 + (size_t)mtg*8192);
    x01 = *(const uint2*)(bw0 + (size_t)(mtg+1)*8192);
    x10 = *(const uint2*)(bw0 + 256 + (size_t)mtg*8192);
    x11 = *(const uint2*)(bw0 + 256 + (size_t)(mtg+1)*8192);
  };

  loadKB(0, aK0, aK1, u00, u01, u10, u11);
  __syncthreads();

  // ---- Q fragments from the conv LDS tile (one-time).
  bf16x8 bQ0 = zfrag, bQ1 = zfrag;
  if (q < 2){
    bQ0 = *(const bf16x8*)&QS[wave*32 + c][q*8];
    bQ1 = *(const bf16x8*)&QS[wave*32 + 16 + c][q*8];
  }

  f32x4 O0[4] = {{0,0,0,0},{0,0,0,0},{0,0,0,0},{0,0,0,0}};
  f32x4 O1[4] = {{0,0,0,0},{0,0,0,0},{0,0,0,0},{0,0,0,0}};
  float ls0 = 0.f, ls1 = 0.f;

  #pragma unroll 1
  for (int win = 0; win < 16; win++){
    // issue next window's V stage load early (T14: write deferred to bottom)
    const int wnext = (win < 15) ? win + 1 : 15;
    bf16x8 sv = *(const bf16x8*)(vbh + (size_t)vr*NPTS + wnext*32 + vc);

    bf16x8 nK0, nK1;
    uint2 m00, m01, m10, m11;
    if (win < 15)
      loadKB(win+1, nK0, nK1, m00, m01, m10, m11);

    // V fragments from LDS (shared by both ntiles, all waves)
    const int vbuf = win & 1;
    bf16x8 V0 = *(const bf16x8*)&VS[vbuf][ 0 + c][q*8];
    bf16x8 V1 = *(const bf16x8*)&VS[vbuf][16 + c][q*8];
    bf16x8 V2 = *(const bf16x8*)&VS[vbuf][32 + c][q*8];
    bf16x8 V3 = *(const bf16x8*)&VS[vbuf][48 + c][q*8];

    f32x4 c00, c01, c10, c11;
    c00[0]=bflo(u00.x); c00[1]=bfhi(u00.x); c00[2]=bflo(u00.y); c00[3]=bfhi(u00.y);
    c01[0]=bflo(u01.x); c01[1]=bfhi(u01.x); c01[2]=bflo(u01.y); c01[3]=bfhi(u01.y);
    c10[0]=bflo(u10.x); c10[1]=bfhi(u10.x); c10[2]=bflo(u10.y); c10[3]=bfhi(u10.y);
    c11[0]=bflo(u11.x); c11[1]=bfhi(u11.x); c11[2]=bflo(u11.y); c11[3]=bfhi(u11.y);
    __builtin_amdgcn_s_setprio(1);
    f32x4 S00 = __builtin_amdgcn_mfma_f32_16x16x32_bf16(aK0, bQ0, c00, 0, 0, 0);
    f32x4 S01 = __builtin_amdgcn_mfma_f32_16x16x32_bf16(aK1, bQ0, c01, 0, 0, 0);
    f32x4 S10 = __builtin_amdgcn_mfma_f32_16x16x32_bf16(aK0, bQ1, c10, 0, 0, 0);
    f32x4 S11 = __builtin_amdgcn_mfma_f32_16x16x32_bf16(aK1, bQ1, c11, 0, 0, 0);
    __builtin_amdgcn_s_setprio(0);

    float e0, e1, e2, e3;
    B8 aP0, aP1;
    e0 = __builtin_amdgcn_exp2f(S00[0]); e1 = __builtin_amdgcn_exp2f(S00[1]);
    e2 = __builtin_amdgcn_exp2f(S00[2]); e3 = __builtin_amdgcn_exp2f(S00[3]);
    ls0 += (e0 + e1) + (e2 + e3);
    aP0.u4.x = pack2bf(e0, e1); aP0.u4.y = pack2bf(e2, e3);
    e0 = __builtin_amdgcn_exp2f(S01[0]); e1 = __builtin_amdgcn_exp2f(S01[1]);
    e2 = __builtin_amdgcn_exp2f(S01[2]); e3 = __builtin_amdgcn_exp2f(S01[3]);
    ls0 += (e0 + e1) + (e2 + e3);
    aP0.u4.z = pack2bf(e0, e1); aP0.u4.w = pack2bf(e2, e3);
    e0 = __builtin_amdgcn_exp2f(S10[0]); e1 = __builtin_amdgcn_exp2f(S10[1]);
    e2 = __builtin_amdgcn_exp2f(S10[2]); e3 = __builtin_amdgcn_exp2f(S10[3]);
    ls1 += (e0 + e1) + (e2 + e3);
    aP1.u4.x = pack2bf(e0, e1); aP1.u4.y = pack2bf(e2, e3);
    e0 = __builtin_amdgcn_exp2f(S11[0]); e1 = __builtin_amdgcn_exp2f(S11[1]);
    e2 = __builtin_amdgcn_exp2f(S11[2]); e3 = __builtin_amdgcn_exp2f(S11[3]);
    ls1 += (e0 + e1) + (e2 + e3);
    aP1.u4.z = pack2bf(e0, e1); aP1.u4.w = pack2bf(e2, e3);

    __builtin_amdgcn_s_setprio(1);
    O0[0] = __builtin_amdgcn_mfma_f32_16x16x32_bf16(aP0.v, V0, O0[0], 0, 0, 0);
    O1[0] = __builtin_amdgcn_mfma_f32_16x16x32_bf16(aP1.v, V0, O1[0], 0, 0, 0);
    O0[1] = __builtin_amdgcn_mfma_f32_16x16x32_bf16(aP0.v, V1, O0[1], 0, 0, 0);
    O1[1] = __builtin_amdgcn_mfma_f32_16x16x32_bf16(aP1.v, V1, O1[1], 0, 0, 0);
    O0[2] = __builtin_amdgcn_mfma_f32_16x16x32_bf16(aP0.v, V2, O0[2], 0, 0, 0);
    O1[2] = __builtin_amdgcn_mfma_f32_16x16x32_bf16(aP1.v, V2, O1[2], 0, 0, 0);
    O0[3] = __builtin_amdgcn_mfma_f32_16x16x32_bf16(aP0.v, V3, O0[3], 0, 0, 0);
    O1[3] = __builtin_amdgcn_mfma_f32_16x16x32_bf16(aP1.v, V3, O1[3], 0, 0, 0);
    __builtin_amdgcn_s_setprio(0);

    // write next window's V tile to the other buffer, then sync.
    if (win < 15)
      *(bf16x8*)&VS[wnext & 1][vr][vc] = sv;
    __syncthreads();

    aK0 = nK0; aK1 = nK1;
    u00 = m00; u01 = m01; u10 = m10; u11 = m11;
  }

  ls0 += __shfl_xor(ls0, 16, 64);
  ls0 += __shfl_xor(ls0, 32, 64);
  ls1 += __shfl_xor(ls1, 16, 64);
  ls1 += __shfl_xor(ls1, 32, 64);
  f32x4 inv0, inv1;
  #pragma unroll
  for (int r = 0; r < 4; r++){
    inv0[r] = 1.0f / __shfl(ls0, q*4 + r, 64);
    inv1[r] = 1.0f / __shfl(ls1, q*4 + r, 64);
  }

  u16* ao = attnout + ((size_t)(b*NPTS + n0))*DH + h*DHEAD;
  #pragma unroll
  for (int dt = 0; dt < 4; dt++)
    #pragma unroll
    for (int r = 0; r < 4; r++){
      ao[(size_t)(q*4 + r)*DH + dt*16 + c] =
          f2bf(fmaxf(O0[dt][r]*inv0[r], 0.f));
      ao[(size_t)(16 + q*4 + r)*DH + dt*16 + c] =
          f2bf(fmaxf(O1[dt][r]*inv1[r], 0.f));
    }
}

// ---------------------------------------------------------------------------
// K4: proj MFMA GEMM. RETILED 64x64 -> grid 1024 = 4 blocks/CU (extending the
// proven 1->2 occupancy win; LDS 16KB/block, A staged once per block,
// L2-resident so doubled A re-reads are cheap). Same LDS 2-phase pipeline,
// XCD swizzle (4 consecutive Mblks share a (b,Nblk) B-panel), direct fp32
// stores. K-accum order unchanged -> bit-identical.
// ---------------------------------------------------------------------------
__global__ __launch_bounds__(256) void k_proj(
    const u16* __restrict__ attn, const u16* __restrict__ pwb,
    const float* __restrict__ bias, float* __restrict__ out)
{
  __shared__ u16 As[2][2048];          // 64 rows x 32 cols
  __shared__ u16 Bs[2][2048];          // 64 rows x 32 cols

  const int blk = blockIdx.x;          // 1024 blocks, XCD-swizzled
  const int xcd = blk & 7;
  const int idx = blk >> 3;            // 0..127
  const int b    = xcd*4 + (idx >> 5); // 4 b's per XCD
  const int inner = idx & 31;
  const int Nblk = inner >> 2;         // 0..7 (64-wide)
  const int Mblk = inner & 3;          // 4 consecutive share (b,Nblk) B-panel

  const int tid = threadIdx.x, wave = tid >> 6, lane = tid & 63;
  const int wm = wave >> 1, wn = wave & 1;
  const int c = lane & 15, q = lane >> 4;
  const int Mbase = Mblk*64 + wm*32;
  const int Nbase = Nblk*64 + wn*32;

  f32x4 acc[2][2];
  #pragma unroll
  for (int mt = 0; mt < 2; mt++){
    f32x4 bi;
    #pragma unroll
    for (int r = 0; r < 4; r++) bi[r] = bias[Mbase + mt*16 + q*4 + r];
    #pragma unroll
    for (int nt = 0; nt < 2; nt++) acc[mt][nt] = bi;
  }

  const u16* aT = pwb + (size_t)(Mblk*64)*DH;
  const u16* bT = attn + ((size_t)b*NPTS + Nblk*64)*DH;

  const int srow = lane >> 2, scol = (lane & 3)*8;

  auto STAGE = [&](int buf, int kc){
    // A: 4 chunks of 16 rows, one per wave; B: same.
    gld16(aT + (size_t)(wave*16 + srow)*DH + kc + scol, &As[buf][wave*512]);
    gld16(bT + (size_t)(wave*16 + srow)*DH + kc + scol, &Bs[buf][wave*512]);
  };

  STAGE(0, 0);
  __syncthreads();

  int cur = 0;
  #pragma unroll 2
  for (int ks = 0; ks < 16; ks++){
    if (ks < 15) STAGE(cur^1, (ks+1)*32);
    bf16x8 aW[2], bA[2];
    #pragma unroll
    for (int mt = 0; mt < 2; mt++)
      aW[mt] = *(const bf16x8*)&As[cur][(wm*32 + mt*16 + c)*32 + q*8];
    #pragma unroll
    for (int nt = 0; nt < 2; nt++)
      bA[nt] = *(const bf16x8*)&Bs[cur][(wn*32 + nt*16 + c)*32 + q*8];
    #pragma unroll
    for (int mt = 0; mt < 2; mt++)
      #pragma unroll
      for (int nt = 0; nt < 2; nt++)
        acc[mt][nt] = __builtin_amdgcn_mfma_f32_16x16x32_bf16(
            aW[mt], bA[nt], acc[mt][nt], 0, 0, 0);
    __syncthreads();
    cur ^= 1;
  }

  #pragma unroll
  for (int mt = 0; mt < 2; mt++){
    #pragma unroll
    for (int nt = 0; nt < 2; nt++){
      const int n = Nbase + nt*16 + c;
      #pragma unroll
      for (int r = 0; r < 4; r++){
        int o = Mbase + mt*16 + q*4 + r;
        out[((size_t)b*DIM + o)*NPTS + n] = acc[mt][nt][r];
      }
    }
  }
}

// ---------------------------------------------------------------------------
extern "C" void kernel_launch(void* const* d_in, const int* in_sizes, int n_in,
                              void* d_out, int out_size, void* d_ws, size_t ws_size,
                              hipStream_t stream)
{
  const float* x     = (const float*)d_in[0];
  const float* qkv_w = (const float*)d_in[1];
  const float* qkv_s = (const float*)d_in[2];
  const float* qkv_b = (const float*)d_in[3];
  const float* dw_w  = (const float*)d_in[4];
  const float* dw_s  = (const float*)d_in[5];
  const float* dw_b  = (const float*)d_in[6];
  const float* ab    = (const float*)d_in[7];
  const float* pw    = (const float*)d_in[8];
  const float* ps    = (const float*)d_in[9];
  const float* pb    = (const float*)d_in[10];
  const int* bidx    = (const int*)d_in[11];

  char* ws = (char*)d_ws;
  u16*   qfb   = (u16*)  (ws);                  //  4 MB (B,128,512) bf16
  u16*   kb    = (u16*)  (ws + ( 8u << 20));    //  4 MB (B,8,512,16) bf16
  u16*   vb    = (u16*)  (ws + (12u << 20));    // 16 MB (B,512,512) bf16 [b][d][p]
  u16*   attn  = (u16*)  (ws + (28u << 20));    // 16 MB (B,512,512) bf16 rows [n][dh]
  u32*   biasb = (u32*)  (ws + (44u << 20));    //  4 MB (8,32,32,64,4) bf16 S^T layout
  u32*   wqb   = (u32*)  (ws + (48u << 20));    // 384 KB (768,256) bf16
  u32*   pwb   = (u32*)  (ws + (49u << 20));    // 256 KB (256,512) bf16
  u16*   xbt   = (u16*)  (ws + (50u << 20));    //  8 MB (B,512,256) bf16 rows

  k_pre <<<dim3(2688),     256, 0, stream>>>(qkv_w, qkv_s, pw, ps, wqb, pwb,
                                             x, xbt, ab, bidx, biasb);
  k_qkv <<<dim3(1536),     256, 0, stream>>>(xbt, (const u16*)wqb, qkv_b, qfb, kb, vb);
  k_attn<<<dim3(256, 4),   256, 0, stream>>>(qfb, kb, vb, (const u16*)biasb,
                                             dw_w, dw_s, dw_b, attn);
  k_proj<<<dim3(1024),     256, 0, stream>>>(attn, (const u16*)pwb, pb, (float*)d_out);
}